// Round 10
// baseline (197.399 us; speedup 1.0000x reference)
//
#include <hip/hip_runtime.h>
#include <hip/hip_fp16.h>

#define NN 50000
#define NE 800000
#define CH 128
#define NG 64
#define OC 10

#define NB 196        // ceil(50000/256) coarse buckets of 256 nodes
#define TILE 4096     // edges per k_bin tile
#define PCAP 8192     // pbuf slots per bucket

typedef _Float16 f16x8 __attribute__((ext_vector_type(8)));
typedef float f32x4 __attribute__((ext_vector_type(4)));

__device__ inline ushort f2h(float x) { __half h = __float2half(x); return __half_as_ushort(h); }
__device__ inline float h2f(ushort u) { return __half2float(__ushort_as_half(u)); }

__device__ inline void h8_unpack(const uint4 u, float* f) {
  f[0] = h2f((ushort)(u.x & 0xffff)); f[1] = h2f((ushort)(u.x >> 16));
  f[2] = h2f((ushort)(u.y & 0xffff)); f[3] = h2f((ushort)(u.y >> 16));
  f[4] = h2f((ushort)(u.z & 0xffff)); f[5] = h2f((ushort)(u.z >> 16));
  f[6] = h2f((ushort)(u.w & 0xffff)); f[7] = h2f((ushort)(u.w >> 16));
}

// ---------------- W fragment prep (+ init duty on block 3) ----------------

__global__ __launch_bounds__(256) void k_prep(const float* __restrict__ W1, const float* __restrict__ W2,
                                              const float* __restrict__ W3, uint4* __restrict__ whf,
                                              int* __restrict__ gcur, float* __restrict__ gsum) {
  if (blockIdx.x == 3) {
    for (int i = threadIdx.x; i < NB; i += 256) gcur[i] = 0;
    for (int i = threadIdx.x; i < NG * CH; i += 256) gsum[i] = 0.f;
    return;
  }
  const float* W = (blockIdx.x == 0) ? W1 : (blockIdx.x == 1) ? W2 : W3;
  uint4* wh = whf + blockIdx.x * 2048;
  for (int idx = threadIdx.x; idx < 2048; idx += 256) {
    int l = idx & 63, f = idx >> 6;
    int ks = f >> 3, nt = f & 7;
    int k0 = ks * 32 + (l >> 4) * 8;
    int col = nt * 16 + (l & 15);
    ushort h[8];
#pragma unroll
    for (int j = 0; j < 8; ++j) h[j] = f2h(W[(k0 + j) * CH + col]);
    uint4 u;
    u.x = (unsigned)h[0] | ((unsigned)h[1] << 16);
    u.y = (unsigned)h[2] | ((unsigned)h[3] << 16);
    u.z = (unsigned)h[4] | ((unsigned)h[5] << 16);
    u.w = (unsigned)h[6] | ((unsigned)h[7] << 16);
    wh[idx] = u;
  }
}

// ---------------- pass 1: bin edges into 196 coarse buckets, LDS-staged ----------------
// packed entry: src (16b) | dst_local (8b) << 16

__global__ __launch_bounds__(256) void k_bin(const int* __restrict__ src, const int* __restrict__ dst,
                                             int* __restrict__ gcur, uint* __restrict__ pbuf) {
  __shared__ int scnt[NB];
  __shared__ int soff[NB];
  __shared__ int gbase[NB];
  __shared__ int ssc[256];
  __shared__ uint pairs[TILE];
  __shared__ unsigned char bid[TILE];
  const int t = threadIdx.x;

  for (int tile0 = blockIdx.x * TILE; tile0 < NE; tile0 += gridDim.x * TILE) {
    const int tcount = min(TILE, NE - tile0);
    for (int i = t; i < NB; i += 256) scnt[i] = 0;
    __syncthreads();
    for (int i = t; i < tcount; i += 256) {
      int d = dst[tile0 + i];
      atomicAdd(&scnt[d >> 8], 1);
    }
    __syncthreads();
    int v = (t < NB) ? scnt[t] : 0;
    ssc[t] = v;
    __syncthreads();
    for (int d2 = 1; d2 < 256; d2 <<= 1) {
      int x2 = (t >= d2) ? ssc[t - d2] : 0;
      __syncthreads();
      ssc[t] += x2;
      __syncthreads();
    }
    if (t < NB) {
      soff[t] = ssc[t] - v;
      gbase[t] = (v > 0) ? atomicAdd(&gcur[t], v) : 0;
      scnt[t] = ssc[t] - v;
    }
    __syncthreads();
    for (int i = t; i < tcount; i += 256) {
      int s = src[tile0 + i], d = dst[tile0 + i];
      int b = d >> 8;
      int pos = atomicAdd(&scnt[b], 1);
      pairs[pos] = (uint)s | ((uint)(d & 255) << 16);
      bid[pos] = (unsigned char)b;
    }
    __syncthreads();
    for (int i = t; i < tcount; i += 256) {
      int b = bid[i];
      pbuf[((size_t)b << 13) + gbase[b] + (i - soff[b])] = pairs[i];
    }
    __syncthreads();
  }
}

// ---------------- pass 2: per-bucket fill -> csrc (u16), rp (+sentinel), dinv ----------------

__global__ __launch_bounds__(256) void k_fill2(const uint* __restrict__ pbuf, const int* __restrict__ gcur,
                                               ushort* __restrict__ csrc, int* __restrict__ rp,
                                               float* __restrict__ dinv) {
  __shared__ int sv[256], ssc[256], loff[256], lcur[256], lcnt[256];
  const int b = blockIdx.x;
  const int t = threadIdx.x;
  const int n0 = b * 256;
  const int nn = min(256, NN - n0);

  // bucket-base scan (all blocks, redundant, cheap)
  int gv = (t < NB) ? gcur[t] : 0;
  sv[t] = gv;
  ssc[t] = gv;
  __syncthreads();
  for (int d = 1; d < 256; d <<= 1) {
    int x = (t >= d) ? ssc[t - d] : 0;
    __syncthreads();
    ssc[t] += x;
    __syncthreads();
  }
  const int beg = ssc[b] - sv[b];
  const int len = sv[b];
  const uint* pb = pbuf + ((size_t)b << 13);
  __syncthreads();

  lcnt[t] = 0;
  __syncthreads();
  for (int i = t; i < len; i += 256) {
    atomicAdd(&lcnt[pb[i] >> 16], 1);
  }
  __syncthreads();
  int v = lcnt[t];
  ssc[t] = v;
  __syncthreads();
  for (int d = 1; d < 256; d <<= 1) {
    int x = (t >= d) ? ssc[t - d] : 0;
    __syncthreads();
    ssc[t] += x;
    __syncthreads();
  }
  loff[t] = ssc[t] - v;
  lcur[t] = ssc[t] - v;
  if (t < nn) {
    rp[n0 + t] = beg + loff[t];
    dinv[n0 + t] = rsqrtf((float)(v + 1));  // +1 self loop
  }
  if (b == NB - 1 && t == nn) rp[NN] = beg + loff[t];  // sentinel = NE
  __syncthreads();
  for (int i = t; i < len; i += 256) {
    uint p = pb[i];
    int slot = atomicAdd(&lcur[p >> 16], 1);
    csrc[beg + slot] = (ushort)(p & 0xffff);
  }
}

// ---------------- GEMM: T' = dinv * (A @ W), LDS-free swapped-operand fp16 MFMA ----------------
// 64 rows/block (grid 782), 4 waves x 1 strip of 16 rows. Zero A-tile reuse across
// waves -> no LDS staging: A fragments loaded global->VGPR directly (clamped row),
// W fragments from pre-swizzled whf (L2-resident). No __syncthreads at all.
// mfma(Wfrag, Afrag): lane holds T[row = strip+(l&15)][col = nt*16 + (l>>4)*4 + i].

template <int IN_HALF>
__global__ __launch_bounds__(256) void k_gemm(const float* __restrict__ Af, const ushort* __restrict__ Ah,
                                              const uint4* __restrict__ whf,
                                              const float* __restrict__ dinv, ushort* __restrict__ T) {
  const int t = threadIdx.x;
  const int w = t >> 6;
  const int l = t & 63;
  const int lr = l & 15;
  const int lk = l >> 4;
  const int row = blockIdx.x * 64 + w * 16 + lr;
  const int rc = min(row, NN - 1);  // clamp OOB loads (stores still guarded)

  f16x8 afr[4];
  if (IN_HALF) {
    const uint4* ar = (const uint4*)(Ah + (size_t)rc * CH);  // 16 uint4 / row
#pragma unroll
    for (int ks = 0; ks < 4; ++ks) {
      afr[ks] = __builtin_bit_cast(f16x8, ar[ks * 4 + lk]);
    }
  } else {
    const float4* ar = (const float4*)(Af + (size_t)rc * CH);  // 32 float4 / row
#pragma unroll
    for (int ks = 0; ks < 4; ++ks) {
      float4 a0 = ar[ks * 8 + lk * 2];
      float4 a1 = ar[ks * 8 + lk * 2 + 1];
      uint4 u;
      u.x = (uint)f2h(a0.x) | ((uint)f2h(a0.y) << 16);
      u.y = (uint)f2h(a0.z) | ((uint)f2h(a0.w) << 16);
      u.z = (uint)f2h(a1.x) | ((uint)f2h(a1.y) << 16);
      u.w = (uint)f2h(a1.z) | ((uint)f2h(a1.w) << 16);
      afr[ks] = __builtin_bit_cast(f16x8, u);
    }
  }

  f32x4 acc[8];
#pragma unroll
  for (int nt = 0; nt < 8; ++nt) acc[nt] = (f32x4)(0.f);

#pragma unroll
  for (int ks = 0; ks < 4; ++ks) {
#pragma unroll
    for (int nt = 0; nt < 8; ++nt) {
      f16x8 bh = __builtin_bit_cast(f16x8, whf[(ks * 8 + nt) * 64 + l]);
      acc[nt] = __builtin_amdgcn_mfma_f32_16x16x32_f16(bh, afr[ks], acc[nt], 0, 0, 0);
    }
  }

  if (row < NN) {
    float d = dinv[row];
    ushort* tr = T + (size_t)row * CH + lk * 4;
#pragma unroll
    for (int nt = 0; nt < 8; ++nt) {
      uint2 pk;
      pk.x = (uint)f2h(acc[nt][0] * d) | ((uint)f2h(acc[nt][1] * d) << 16);
      pk.y = (uint)f2h(acc[nt][2] * d) | ((uint)f2h(acc[nt][3] * d) << 16);
      *(uint2*)(tr + nt * 16) = pk;
    }
  }
}

// ---------------- Aggregation: quarter-wave per node, unroll 4 ----------------
// 16 lanes x 16B = full 256B row; num from rp sentinel; u16 csrc.
// MODE 0: out = fp16 relu(...). MODE 1: out = fp32 (n_emb).

template <int MODE>
__global__ __launch_bounds__(256) void k_agg(const ushort* __restrict__ Tp, const int* __restrict__ rp,
                                             const ushort* __restrict__ csrc,
                                             const float* __restrict__ dinv, const float* __restrict__ b,
                                             ushort* __restrict__ outh, float* __restrict__ outf) {
  const int node = blockIdx.x * 16 + (threadIdx.x >> 4);  // grid exact: 3125*16
  const int q = threadIdx.x & 15;                          // channels 8q..8q+7
  const uint4* T16 = (const uint4*)Tp;

  float a[8];
  h8_unpack(T16[(size_t)node * 16 + q], a);  // self term

  const int beg = rp[node];
  const int num = rp[node + 1] - beg;
  int e = 0;
  for (; e + 3 < num; e += 4) {
    int s0 = csrc[beg + e];
    int s1 = csrc[beg + e + 1];
    int s2 = csrc[beg + e + 2];
    int s3 = csrc[beg + e + 3];
    uint4 m0 = T16[(size_t)s0 * 16 + q];
    uint4 m1 = T16[(size_t)s1 * 16 + q];
    uint4 m2 = T16[(size_t)s2 * 16 + q];
    uint4 m3 = T16[(size_t)s3 * 16 + q];
    float f0[8], f1[8], f2[8], f3[8];
    h8_unpack(m0, f0); h8_unpack(m1, f1); h8_unpack(m2, f2); h8_unpack(m3, f3);
#pragma unroll
    for (int j = 0; j < 8; ++j) a[j] += (f0[j] + f1[j]) + (f2[j] + f3[j]);
  }
  for (; e < num; ++e) {
    int s = csrc[beg + e];
    float f[8];
    h8_unpack(T16[(size_t)s * 16 + q], f);
#pragma unroll
    for (int j = 0; j < 8; ++j) a[j] += f[j];
  }

  const float d = dinv[node];
  float4 bb0 = ((const float4*)b)[q * 2];
  float4 bb1 = ((const float4*)b)[q * 2 + 1];
  float o[8];
  o[0] = fmaf(d, a[0], bb0.x); o[1] = fmaf(d, a[1], bb0.y);
  o[2] = fmaf(d, a[2], bb0.z); o[3] = fmaf(d, a[3], bb0.w);
  o[4] = fmaf(d, a[4], bb1.x); o[5] = fmaf(d, a[5], bb1.y);
  o[6] = fmaf(d, a[6], bb1.z); o[7] = fmaf(d, a[7], bb1.w);

  if (MODE == 0) {
    uint4 p;
    p.x = (unsigned)f2h(fmaxf(o[0], 0.f)) | ((unsigned)f2h(fmaxf(o[1], 0.f)) << 16);
    p.y = (unsigned)f2h(fmaxf(o[2], 0.f)) | ((unsigned)f2h(fmaxf(o[3], 0.f)) << 16);
    p.z = (unsigned)f2h(fmaxf(o[4], 0.f)) | ((unsigned)f2h(fmaxf(o[5], 0.f)) << 16);
    p.w = (unsigned)f2h(fmaxf(o[6], 0.f)) | ((unsigned)f2h(fmaxf(o[7], 0.f)) << 16);
    ((uint4*)outh)[(size_t)node * 16 + q] = p;
  } else {
    float4* of = (float4*)outf;
    of[(size_t)node * 32 + q * 2] = make_float4(o[0], o[1], o[2], o[3]);
    of[(size_t)node * 32 + q * 2 + 1] = make_float4(o[4], o[5], o[6], o[7]);
  }
}

// ---------------- Pool (2-stage) + final linear ----------------

#define PCHUNK 32

__global__ __launch_bounds__(128) void k_pool1(const float* __restrict__ nemb,
                                               const int* __restrict__ batch,
                                               float* __restrict__ gsum) {
  int g = blockIdx.x >> 5;
  int ck = blockIdx.x & (PCHUNK - 1);
  int c = threadIdx.x;
  int lo = 0, hi = NN;
  while (lo < hi) { int m = (lo + hi) >> 1; if (batch[m] < g) lo = m + 1; else hi = m; }
  int beg = lo;
  hi = NN;
  while (lo < hi) { int m = (lo + hi) >> 1; if (batch[m] < g + 1) lo = m + 1; else hi = m; }
  int end = lo;
  int len = end - beg;
  int c0 = beg + (int)(((long long)len * ck) >> 5);
  int c1 = beg + (int)(((long long)len * (ck + 1)) >> 5);
  float sum = 0.f;
  for (int n = c0; n < c1; ++n) sum += nemb[(size_t)n * CH + c];
  atomicAdd(&gsum[g * CH + c], sum);
}

__global__ __launch_bounds__(128) void k_pool2(const float* __restrict__ gsum,
                                               const int* __restrict__ batch,
                                               const float* __restrict__ Wl,
                                               const float* __restrict__ bl,
                                               float* __restrict__ gout) {
  int g = blockIdx.x;
  int c = threadIdx.x;
  int lo = 0, hi = NN;
  while (lo < hi) { int m = (lo + hi) >> 1; if (batch[m] < g) lo = m + 1; else hi = m; }
  int beg = lo;
  hi = NN;
  while (lo < hi) { int m = (lo + hi) >> 1; if (batch[m] < g + 1) lo = m + 1; else hi = m; }
  int end = lo;
  float gv = gsum[g * CH + c] / fmaxf((float)(end - beg), 1.0f);

  __shared__ float sg[CH];
  sg[c] = gv;
  __syncthreads();
  if (c < OC) {
    float o = bl[c];
    for (int k = 0; k < CH; ++k) o = fmaf(sg[k], Wl[k * OC + c], o);
    gout[g * OC + c] = o;
  }
}

// ---------------- launch ----------------

extern "C" void kernel_launch(void* const* d_in, const int* in_sizes, int n_in,
                              void* d_out, int out_size, void* d_ws, size_t ws_size,
                              hipStream_t stream) {
  const float* x = (const float*)d_in[0];
  const int* ei = (const int*)d_in[1];
  const int* src = ei;
  const int* dst = ei + NE;
  const int* batch = (const int*)d_in[2];
  const float* W1 = (const float*)d_in[3];
  const float* b1 = (const float*)d_in[4];
  const float* W2 = (const float*)d_in[5];
  const float* b2 = (const float*)d_in[6];
  const float* W3 = (const float*)d_in[7];
  const float* b3 = (const float*)d_in[8];
  const float* Wl = (const float*)d_in[9];
  const float* bl = (const float*)d_in[10];

  char* ws = (char*)d_ws;
  size_t off = 0;
  auto alloc = [&](size_t bytes) {
    void* p = ws + off;
    off += (bytes + 255) & ~(size_t)255;
    return p;
  };
  float* dinv = (float*)alloc(NN * 4);
  int* rp = (int*)alloc((NN + 1) * 4);
  int* gcur = (int*)alloc(NB * 4);
  ushort* csrc = (ushort*)alloc((size_t)NE * 2);          // 1.6 MB (u16 src ids)
  uint* pbuf = (uint*)alloc((size_t)NB * PCAP * 4);       // 6.4 MB packed
  ushort* thalf = (ushort*)alloc((size_t)NN * CH * 2);    // T' fp16
  ushort* hhalf = (ushort*)alloc((size_t)NN * CH * 2);    // h fp16 (relu'd)
  float* gsum = (float*)alloc((size_t)NG * CH * 4);
  uint4* whf = (uint4*)alloc(3 * 2048 * sizeof(uint4));   // 96 KB fp16 W frags

  float* gout = (float*)d_out;
  float* nemb = (float*)d_out + NG * OC;

  const int nb_g = (NN + 63) / 64;          // 782
  const int nb_a = NN / 16;                 // 3125
  const int nb_t = (NE + TILE - 1) / TILE;  // 196 bin tiles

  k_prep<<<4, 256, 0, stream>>>(W1, W2, W3, whf, gcur, gsum);  // + zero duty
  k_bin<<<nb_t, 256, 0, stream>>>(src, dst, gcur, pbuf);
  k_fill2<<<NB, 256, 0, stream>>>(pbuf, gcur, csrc, rp, dinv);

  // layer 1: T' = dinv*(x @ W1); h = relu(b1 + dinv*(T'self + sum T'src)) -> fp16
  k_gemm<0><<<nb_g, 256, 0, stream>>>(x, nullptr, whf + 0 * 2048, dinv, thalf);
  k_agg<0><<<nb_a, 256, 0, stream>>>(thalf, rp, csrc, dinv, b1, hhalf, nullptr);
  // layer 2
  k_gemm<1><<<nb_g, 256, 0, stream>>>(nullptr, hhalf, whf + 1 * 2048, dinv, thalf);
  k_agg<0><<<nb_a, 256, 0, stream>>>(thalf, rp, csrc, dinv, b2, hhalf, nullptr);
  // layer 3 -> n_emb fp32 straight into d_out (no relu)
  k_gemm<1><<<nb_g, 256, 0, stream>>>(nullptr, hhalf, whf + 2 * 2048, dinv, thalf);
  k_agg<1><<<nb_a, 256, 0, stream>>>(thalf, rp, csrc, dinv, b3, nullptr, nemb);
  // pool
  k_pool1<<<NG * PCHUNK, 128, 0, stream>>>(nemb, batch, gsum);
  k_pool2<<<NG, 128, 0, stream>>>(gsum, batch, Wl, bl, gout);
}

// Round 11
// 181.811 us; speedup vs baseline: 1.0857x; 1.0857x over previous
//
#include <hip/hip_runtime.h>
#include <hip/hip_fp16.h>

#define NN 50000
#define NE 800000
#define CH 128
#define NG 64
#define OC 10

#define NB 196        // ceil(50000/256) coarse buckets of 256 nodes
#define TILE 4096     // edges per k_bin tile
#define PCAP 8192     // pbuf slots per bucket
#define EPT 16        // edges per thread in k_bin (TILE/256)

typedef _Float16 f16x8 __attribute__((ext_vector_type(8)));
typedef float f32x4 __attribute__((ext_vector_type(4)));

__device__ inline ushort f2h(float x) { __half h = __float2half(x); return __half_as_ushort(h); }
__device__ inline float h2f(ushort u) { return __half2float(__ushort_as_half(u)); }

__device__ inline void h8_unpack(const uint4 u, float* f) {
  f[0] = h2f((ushort)(u.x & 0xffff)); f[1] = h2f((ushort)(u.x >> 16));
  f[2] = h2f((ushort)(u.y & 0xffff)); f[3] = h2f((ushort)(u.y >> 16));
  f[4] = h2f((ushort)(u.z & 0xffff)); f[5] = h2f((ushort)(u.z >> 16));
  f[6] = h2f((ushort)(u.w & 0xffff)); f[7] = h2f((ushort)(u.w >> 16));
}

// ---------------- W fragment prep (+ init duty on block 3) ----------------

__global__ __launch_bounds__(256) void k_prep(const float* __restrict__ W1, const float* __restrict__ W2,
                                              const float* __restrict__ W3, uint4* __restrict__ whf,
                                              int* __restrict__ gcur, float* __restrict__ gsum) {
  if (blockIdx.x == 3) {
    for (int i = threadIdx.x; i < NB; i += 256) gcur[i] = 0;
    for (int i = threadIdx.x; i < NG * CH; i += 256) gsum[i] = 0.f;
    return;
  }
  const float* W = (blockIdx.x == 0) ? W1 : (blockIdx.x == 1) ? W2 : W3;
  uint4* wh = whf + blockIdx.x * 2048;
  for (int idx = threadIdx.x; idx < 2048; idx += 256) {
    int l = idx & 63, f = idx >> 6;
    int ks = f >> 3, nt = f & 7;
    int k0 = ks * 32 + (l >> 4) * 8;
    int col = nt * 16 + (l & 15);
    ushort h[8];
#pragma unroll
    for (int j = 0; j < 8; ++j) h[j] = f2h(W[(k0 + j) * CH + col]);
    uint4 u;
    u.x = (unsigned)h[0] | ((unsigned)h[1] << 16);
    u.y = (unsigned)h[2] | ((unsigned)h[3] << 16);
    u.z = (unsigned)h[4] | ((unsigned)h[5] << 16);
    u.w = (unsigned)h[6] | ((unsigned)h[7] << 16);
    wh[idx] = u;
  }
}

// ---------------- pass 1: bin edges into 196 coarse buckets, LDS-staged ----------------
// one tile (4096 edges) per block; edges register-cached (src+dst read once).
// packed entry: src (16b) | dst_local (8b) << 16

__global__ __launch_bounds__(256) void k_bin(const int* __restrict__ src, const int* __restrict__ dst,
                                             int* __restrict__ gcur, uint* __restrict__ pbuf) {
  __shared__ int scnt[NB];
  __shared__ int soff[NB];
  __shared__ int gbase[NB];
  __shared__ int ssc[256];
  __shared__ uint pairs[TILE];
  __shared__ unsigned char bid[TILE];
  const int t = threadIdx.x;
  const int tile0 = blockIdx.x * TILE;
  const int tcount = min(TILE, NE - tile0);

  int myd[EPT], mys[EPT];
#pragma unroll
  for (int k = 0; k < EPT; ++k) {
    int i = t + k * 256;
    if (i < tcount) {
      myd[k] = dst[tile0 + i];
      mys[k] = src[tile0 + i];
    } else {
      myd[k] = -1;
    }
  }

  for (int i = t; i < NB; i += 256) scnt[i] = 0;
  __syncthreads();
#pragma unroll
  for (int k = 0; k < EPT; ++k) {
    if (myd[k] >= 0) atomicAdd(&scnt[myd[k] >> 8], 1);
  }
  __syncthreads();
  int v = (t < NB) ? scnt[t] : 0;
  ssc[t] = v;
  __syncthreads();
  for (int d2 = 1; d2 < 256; d2 <<= 1) {
    int x2 = (t >= d2) ? ssc[t - d2] : 0;
    __syncthreads();
    ssc[t] += x2;
    __syncthreads();
  }
  if (t < NB) {
    soff[t] = ssc[t] - v;
    gbase[t] = (v > 0) ? atomicAdd(&gcur[t], v) : 0;
    scnt[t] = ssc[t] - v;
  }
  __syncthreads();
#pragma unroll
  for (int k = 0; k < EPT; ++k) {
    if (myd[k] >= 0) {
      int b = myd[k] >> 8;
      int pos = atomicAdd(&scnt[b], 1);
      pairs[pos] = (uint)mys[k] | ((uint)(myd[k] & 255) << 16);
      bid[pos] = (unsigned char)b;
    }
  }
  __syncthreads();
  for (int i = t; i < tcount; i += 256) {
    int b = bid[i];
    pbuf[((size_t)b << 13) + gbase[b] + (i - soff[b])] = pairs[i];
  }
}

// ---------------- pass 2: per-bucket fill -> csrc (u16), rp (+sentinel), dinv ----------------

__global__ __launch_bounds__(256) void k_fill2(const uint* __restrict__ pbuf, const int* __restrict__ gcur,
                                               ushort* __restrict__ csrc, int* __restrict__ rp,
                                               float* __restrict__ dinv) {
  __shared__ int sv[256], ssc[256], loff[256], lcur[256], lcnt[256];
  const int b = blockIdx.x;
  const int t = threadIdx.x;
  const int n0 = b * 256;
  const int nn = min(256, NN - n0);

  int gv = (t < NB) ? gcur[t] : 0;
  sv[t] = gv;
  ssc[t] = gv;
  __syncthreads();
  for (int d = 1; d < 256; d <<= 1) {
    int x = (t >= d) ? ssc[t - d] : 0;
    __syncthreads();
    ssc[t] += x;
    __syncthreads();
  }
  const int beg = ssc[b] - sv[b];
  const int len = sv[b];
  const uint* pb = pbuf + ((size_t)b << 13);
  __syncthreads();

  lcnt[t] = 0;
  __syncthreads();
  for (int i = t; i < len; i += 256) {
    atomicAdd(&lcnt[pb[i] >> 16], 1);
  }
  __syncthreads();
  int v = lcnt[t];
  ssc[t] = v;
  __syncthreads();
  for (int d = 1; d < 256; d <<= 1) {
    int x = (t >= d) ? ssc[t - d] : 0;
    __syncthreads();
    ssc[t] += x;
    __syncthreads();
  }
  loff[t] = ssc[t] - v;
  lcur[t] = ssc[t] - v;
  if (t < nn) {
    rp[n0 + t] = beg + loff[t];
    dinv[n0 + t] = rsqrtf((float)(v + 1));  // +1 self loop
  }
  if (b == NB - 1 && t == nn) rp[NN] = beg + loff[t];  // sentinel = NE
  __syncthreads();
  for (int i = t; i < len; i += 256) {
    uint p = pb[i];
    int slot = atomicAdd(&lcur[p >> 16], 1);
    csrc[beg + slot] = (ushort)(p & 0xffff);
  }
}

// ---------------- GEMM: T' = dinv * (A @ W), LDS-free swapped-operand fp16 MFMA ----------------

template <int IN_HALF>
__global__ __launch_bounds__(256) void k_gemm(const float* __restrict__ Af, const ushort* __restrict__ Ah,
                                              const uint4* __restrict__ whf,
                                              const float* __restrict__ dinv, ushort* __restrict__ T) {
  const int t = threadIdx.x;
  const int w = t >> 6;
  const int l = t & 63;
  const int lr = l & 15;
  const int lk = l >> 4;
  const int row = blockIdx.x * 64 + w * 16 + lr;
  const int rc = min(row, NN - 1);  // clamp OOB loads (stores still guarded)

  f16x8 afr[4];
  if (IN_HALF) {
    const uint4* ar = (const uint4*)(Ah + (size_t)rc * CH);
#pragma unroll
    for (int ks = 0; ks < 4; ++ks) {
      afr[ks] = __builtin_bit_cast(f16x8, ar[ks * 4 + lk]);
    }
  } else {
    const float4* ar = (const float4*)(Af + (size_t)rc * CH);
#pragma unroll
    for (int ks = 0; ks < 4; ++ks) {
      float4 a0 = ar[ks * 8 + lk * 2];
      float4 a1 = ar[ks * 8 + lk * 2 + 1];
      uint4 u;
      u.x = (uint)f2h(a0.x) | ((uint)f2h(a0.y) << 16);
      u.y = (uint)f2h(a0.z) | ((uint)f2h(a0.w) << 16);
      u.z = (uint)f2h(a1.x) | ((uint)f2h(a1.y) << 16);
      u.w = (uint)f2h(a1.z) | ((uint)f2h(a1.w) << 16);
      afr[ks] = __builtin_bit_cast(f16x8, u);
    }
  }

  f32x4 acc[8];
#pragma unroll
  for (int nt = 0; nt < 8; ++nt) acc[nt] = (f32x4)(0.f);

#pragma unroll
  for (int ks = 0; ks < 4; ++ks) {
#pragma unroll
    for (int nt = 0; nt < 8; ++nt) {
      f16x8 bh = __builtin_bit_cast(f16x8, whf[(ks * 8 + nt) * 64 + l]);
      acc[nt] = __builtin_amdgcn_mfma_f32_16x16x32_f16(bh, afr[ks], acc[nt], 0, 0, 0);
    }
  }

  if (row < NN) {
    float d = dinv[row];
    ushort* tr = T + (size_t)row * CH + lk * 4;
#pragma unroll
    for (int nt = 0; nt < 8; ++nt) {
      uint2 pk;
      pk.x = (uint)f2h(acc[nt][0] * d) | ((uint)f2h(acc[nt][1] * d) << 16);
      pk.y = (uint)f2h(acc[nt][2] * d) | ((uint)f2h(acc[nt][3] * d) << 16);
      *(uint2*)(tr + nt * 16) = pk;
    }
  }
}

// ---------------- Aggregation: quarter-wave per node, unroll 4 ----------------
// MODE 0: out = fp16 relu(...) -> outh.
// MODE 1: out = fp32 n_emb -> outf, PLUS fused mean-pool partial: block stages its
// 16 node outputs in LDS, run-accumulates along sorted batch ids, atomicAdds gsum.

template <int MODE>
__global__ __launch_bounds__(256) void k_agg(const ushort* __restrict__ Tp, const int* __restrict__ rp,
                                             const ushort* __restrict__ csrc,
                                             const float* __restrict__ dinv, const float* __restrict__ b,
                                             ushort* __restrict__ outh, float* __restrict__ outf,
                                             const int* __restrict__ batch, float* __restrict__ gsum) {
  const int nb = threadIdx.x >> 4;                 // node-in-block 0..15
  const int node = blockIdx.x * 16 + nb;           // grid exact: 3125*16
  const int q = threadIdx.x & 15;                  // channels 8q..8q+7
  const uint4* T16 = (const uint4*)Tp;

  float a[8];
  h8_unpack(T16[(size_t)node * 16 + q], a);  // self term

  const int beg = rp[node];
  const int num = rp[node + 1] - beg;
  int e = 0;
  for (; e + 3 < num; e += 4) {
    int s0 = csrc[beg + e];
    int s1 = csrc[beg + e + 1];
    int s2 = csrc[beg + e + 2];
    int s3 = csrc[beg + e + 3];
    uint4 m0 = T16[(size_t)s0 * 16 + q];
    uint4 m1 = T16[(size_t)s1 * 16 + q];
    uint4 m2 = T16[(size_t)s2 * 16 + q];
    uint4 m3 = T16[(size_t)s3 * 16 + q];
    float f0[8], f1[8], f2[8], f3[8];
    h8_unpack(m0, f0); h8_unpack(m1, f1); h8_unpack(m2, f2); h8_unpack(m3, f3);
#pragma unroll
    for (int j = 0; j < 8; ++j) a[j] += (f0[j] + f1[j]) + (f2[j] + f3[j]);
  }
  for (; e < num; ++e) {
    int s = csrc[beg + e];
    float f[8];
    h8_unpack(T16[(size_t)s * 16 + q], f);
#pragma unroll
    for (int j = 0; j < 8; ++j) a[j] += f[j];
  }

  const float d = dinv[node];
  float4 bb0 = ((const float4*)b)[q * 2];
  float4 bb1 = ((const float4*)b)[q * 2 + 1];
  float o[8];
  o[0] = fmaf(d, a[0], bb0.x); o[1] = fmaf(d, a[1], bb0.y);
  o[2] = fmaf(d, a[2], bb0.z); o[3] = fmaf(d, a[3], bb0.w);
  o[4] = fmaf(d, a[4], bb1.x); o[5] = fmaf(d, a[5], bb1.y);
  o[6] = fmaf(d, a[6], bb1.z); o[7] = fmaf(d, a[7], bb1.w);

  if (MODE == 0) {
    uint4 p;
    p.x = (unsigned)f2h(fmaxf(o[0], 0.f)) | ((unsigned)f2h(fmaxf(o[1], 0.f)) << 16);
    p.y = (unsigned)f2h(fmaxf(o[2], 0.f)) | ((unsigned)f2h(fmaxf(o[3], 0.f)) << 16);
    p.z = (unsigned)f2h(fmaxf(o[4], 0.f)) | ((unsigned)f2h(fmaxf(o[5], 0.f)) << 16);
    p.w = (unsigned)f2h(fmaxf(o[6], 0.f)) | ((unsigned)f2h(fmaxf(o[7], 0.f)) << 16);
    ((uint4*)outh)[(size_t)node * 16 + q] = p;
  } else {
    float4* of = (float4*)outf;
    of[(size_t)node * 32 + q * 2] = make_float4(o[0], o[1], o[2], o[3]);
    of[(size_t)node * 32 + q * 2 + 1] = make_float4(o[4], o[5], o[6], o[7]);

    // fused mean-pool partial
    __shared__ float oall[16][CH];
    __shared__ int gids[16];
    *(float4*)&oall[nb][q * 8] = make_float4(o[0], o[1], o[2], o[3]);
    *(float4*)&oall[nb][q * 8 + 4] = make_float4(o[4], o[5], o[6], o[7]);
    if (q == 0) gids[nb] = batch[node];
    __syncthreads();
    // 256 threads: channel c = t & 127, half rows [half*8, half*8+8)
    const int c = threadIdx.x & 127;
    const int half = threadIdx.x >> 7;
    int curg = gids[half * 8];
    float run = 0.f;
#pragma unroll
    for (int n = 0; n < 8; ++n) {
      int r = half * 8 + n;
      int g = gids[r];
      if (g != curg) {
        atomicAdd(&gsum[curg * CH + c], run);
        run = 0.f;
        curg = g;
      }
      run += oall[r][c];
    }
    atomicAdd(&gsum[curg * CH + c], run);
  }
}

// ---------------- Pool finish: divide by count + g @ Wl + bl ----------------

__global__ __launch_bounds__(128) void k_pool2(const float* __restrict__ gsum,
                                               const int* __restrict__ batch,
                                               const float* __restrict__ Wl,
                                               const float* __restrict__ bl,
                                               float* __restrict__ gout) {
  int g = blockIdx.x;
  int c = threadIdx.x;
  int lo = 0, hi = NN;
  while (lo < hi) { int m = (lo + hi) >> 1; if (batch[m] < g) lo = m + 1; else hi = m; }
  int beg = lo;
  hi = NN;
  while (lo < hi) { int m = (lo + hi) >> 1; if (batch[m] < g + 1) lo = m + 1; else hi = m; }
  int end = lo;
  float gv = gsum[g * CH + c] / fmaxf((float)(end - beg), 1.0f);

  __shared__ float sg[CH];
  sg[c] = gv;
  __syncthreads();
  if (c < OC) {
    float o = bl[c];
    for (int k = 0; k < CH; ++k) o = fmaf(sg[k], Wl[k * OC + c], o);
    gout[g * OC + c] = o;
  }
}

// ---------------- launch ----------------

extern "C" void kernel_launch(void* const* d_in, const int* in_sizes, int n_in,
                              void* d_out, int out_size, void* d_ws, size_t ws_size,
                              hipStream_t stream) {
  const float* x = (const float*)d_in[0];
  const int* ei = (const int*)d_in[1];
  const int* src = ei;
  const int* dst = ei + NE;
  const int* batch = (const int*)d_in[2];
  const float* W1 = (const float*)d_in[3];
  const float* b1 = (const float*)d_in[4];
  const float* W2 = (const float*)d_in[5];
  const float* b2 = (const float*)d_in[6];
  const float* W3 = (const float*)d_in[7];
  const float* b3 = (const float*)d_in[8];
  const float* Wl = (const float*)d_in[9];
  const float* bl = (const float*)d_in[10];

  char* ws = (char*)d_ws;
  size_t off = 0;
  auto alloc = [&](size_t bytes) {
    void* p = ws + off;
    off += (bytes + 255) & ~(size_t)255;
    return p;
  };
  float* dinv = (float*)alloc(NN * 4);
  int* rp = (int*)alloc((NN + 1) * 4);
  int* gcur = (int*)alloc(NB * 4);
  ushort* csrc = (ushort*)alloc((size_t)NE * 2);          // 1.6 MB (u16 src ids)
  uint* pbuf = (uint*)alloc((size_t)NB * PCAP * 4);       // 6.4 MB packed
  ushort* thalf = (ushort*)alloc((size_t)NN * CH * 2);    // T' fp16
  ushort* hhalf = (ushort*)alloc((size_t)NN * CH * 2);    // h fp16 (relu'd)
  float* gsum = (float*)alloc((size_t)NG * CH * 4);
  uint4* whf = (uint4*)alloc(3 * 2048 * sizeof(uint4));   // 96 KB fp16 W frags

  float* gout = (float*)d_out;
  float* nemb = (float*)d_out + NG * OC;

  const int nb_g = (NN + 63) / 64;          // 782
  const int nb_a = NN / 16;                 // 3125
  const int nb_t = (NE + TILE - 1) / TILE;  // 196 bin tiles

  k_prep<<<4, 256, 0, stream>>>(W1, W2, W3, whf, gcur, gsum);  // + zero duty
  k_bin<<<nb_t, 256, 0, stream>>>(src, dst, gcur, pbuf);
  k_fill2<<<NB, 256, 0, stream>>>(pbuf, gcur, csrc, rp, dinv);

  // layer 1: T' = dinv*(x @ W1); h = relu(b1 + dinv*(T'self + sum T'src)) -> fp16
  k_gemm<0><<<nb_g, 256, 0, stream>>>(x, nullptr, whf + 0 * 2048, dinv, thalf);
  k_agg<0><<<nb_a, 256, 0, stream>>>(thalf, rp, csrc, dinv, b1, hhalf, nullptr, nullptr, nullptr);
  // layer 2
  k_gemm<1><<<nb_g, 256, 0, stream>>>(nullptr, hhalf, whf + 1 * 2048, dinv, thalf);
  k_agg<0><<<nb_a, 256, 0, stream>>>(thalf, rp, csrc, dinv, b2, hhalf, nullptr, nullptr, nullptr);
  // layer 3 -> n_emb fp32 into d_out + fused pool partial into gsum
  k_gemm<1><<<nb_g, 256, 0, stream>>>(nullptr, hhalf, whf + 2 * 2048, dinv, thalf);
  k_agg<1><<<nb_a, 256, 0, stream>>>(thalf, rp, csrc, dinv, b3, nullptr, nemb, batch, gsum);
  // pool finish
  k_pool2<<<NG, 128, 0, stream>>>(gsum, batch, Wl, bl, gout);
}

// Round 12
// 170.799 us; speedup vs baseline: 1.1557x; 1.0645x over previous
//
#include <hip/hip_runtime.h>
#include <hip/hip_fp16.h>

#define NN 50000
#define NE 800000
#define CH 128
#define NG 64
#define OC 10

#define NB 196        // ceil(50000/256) coarse buckets of 256 nodes
#define TILE 4096     // edges per k_bin tile
#define PCAP 8192     // pbuf slots per bucket
#define EPT 16        // edges per thread in k_bin (TILE/256)

typedef _Float16 f16x8 __attribute__((ext_vector_type(8)));
typedef float f32x4 __attribute__((ext_vector_type(4)));

__device__ inline ushort f2h(float x) { __half h = __float2half(x); return __half_as_ushort(h); }
__device__ inline float h2f(ushort u) { return __half2float(__ushort_as_half(u)); }

__device__ inline void h8_unpack(const uint4 u, float* f) {
  f[0] = h2f((ushort)(u.x & 0xffff)); f[1] = h2f((ushort)(u.x >> 16));
  f[2] = h2f((ushort)(u.y & 0xffff)); f[3] = h2f((ushort)(u.y >> 16));
  f[4] = h2f((ushort)(u.z & 0xffff)); f[5] = h2f((ushort)(u.z >> 16));
  f[6] = h2f((ushort)(u.w & 0xffff)); f[7] = h2f((ushort)(u.w >> 16));
}

// shared gather body: accumulate sum of T'[src] rows into a[8] (channels 8q..8q+7)
__device__ inline void gather_acc(const uint4* __restrict__ T16, const ushort* __restrict__ csrc,
                                  int beg, int num, int q, float* a) {
  int e = 0;
  for (; e + 3 < num; e += 4) {
    int s0 = csrc[beg + e];
    int s1 = csrc[beg + e + 1];
    int s2 = csrc[beg + e + 2];
    int s3 = csrc[beg + e + 3];
    uint4 m0 = T16[(size_t)s0 * 16 + q];
    uint4 m1 = T16[(size_t)s1 * 16 + q];
    uint4 m2 = T16[(size_t)s2 * 16 + q];
    uint4 m3 = T16[(size_t)s3 * 16 + q];
    float f0[8], f1[8], f2[8], f3[8];
    h8_unpack(m0, f0); h8_unpack(m1, f1); h8_unpack(m2, f2); h8_unpack(m3, f3);
#pragma unroll
    for (int j = 0; j < 8; ++j) a[j] += (f0[j] + f1[j]) + (f2[j] + f3[j]);
  }
  for (; e < num; ++e) {
    int s = csrc[beg + e];
    float f[8];
    h8_unpack(T16[(size_t)s * 16 + q], f);
#pragma unroll
    for (int j = 0; j < 8; ++j) a[j] += f[j];
  }
}

// ---------------- W fragment prep (+ init duty on block 3) ----------------

__global__ __launch_bounds__(256) void k_prep(const float* __restrict__ W1, const float* __restrict__ W2,
                                              const float* __restrict__ W3, uint4* __restrict__ whf,
                                              int* __restrict__ gcur, float* __restrict__ gsum) {
  if (blockIdx.x == 3) {
    for (int i = threadIdx.x; i < NB; i += 256) gcur[i] = 0;
    for (int i = threadIdx.x; i < NG * CH; i += 256) gsum[i] = 0.f;
    return;
  }
  const float* W = (blockIdx.x == 0) ? W1 : (blockIdx.x == 1) ? W2 : W3;
  uint4* wh = whf + blockIdx.x * 2048;
  for (int idx = threadIdx.x; idx < 2048; idx += 256) {
    int l = idx & 63, f = idx >> 6;
    int ks = f >> 3, nt = f & 7;
    int k0 = ks * 32 + (l >> 4) * 8;
    int col = nt * 16 + (l & 15);
    ushort h[8];
#pragma unroll
    for (int j = 0; j < 8; ++j) h[j] = f2h(W[(k0 + j) * CH + col]);
    uint4 u;
    u.x = (unsigned)h[0] | ((unsigned)h[1] << 16);
    u.y = (unsigned)h[2] | ((unsigned)h[3] << 16);
    u.z = (unsigned)h[4] | ((unsigned)h[5] << 16);
    u.w = (unsigned)h[6] | ((unsigned)h[7] << 16);
    wh[idx] = u;
  }
}

// ---------------- pass 1: bin edges into 196 coarse buckets, LDS-staged ----------------

__global__ __launch_bounds__(256) void k_bin(const int* __restrict__ src, const int* __restrict__ dst,
                                             int* __restrict__ gcur, uint* __restrict__ pbuf) {
  __shared__ int scnt[NB];
  __shared__ int soff[NB];
  __shared__ int gbase[NB];
  __shared__ int ssc[256];
  __shared__ uint pairs[TILE];
  __shared__ unsigned char bid[TILE];
  const int t = threadIdx.x;
  const int tile0 = blockIdx.x * TILE;
  const int tcount = min(TILE, NE - tile0);

  int myd[EPT], mys[EPT];
#pragma unroll
  for (int k = 0; k < EPT; ++k) {
    int i = t + k * 256;
    if (i < tcount) {
      myd[k] = dst[tile0 + i];
      mys[k] = src[tile0 + i];
    } else {
      myd[k] = -1;
    }
  }

  for (int i = t; i < NB; i += 256) scnt[i] = 0;
  __syncthreads();
#pragma unroll
  for (int k = 0; k < EPT; ++k) {
    if (myd[k] >= 0) atomicAdd(&scnt[myd[k] >> 8], 1);
  }
  __syncthreads();
  int v = (t < NB) ? scnt[t] : 0;
  ssc[t] = v;
  __syncthreads();
  for (int d2 = 1; d2 < 256; d2 <<= 1) {
    int x2 = (t >= d2) ? ssc[t - d2] : 0;
    __syncthreads();
    ssc[t] += x2;
    __syncthreads();
  }
  if (t < NB) {
    soff[t] = ssc[t] - v;
    gbase[t] = (v > 0) ? atomicAdd(&gcur[t], v) : 0;
    scnt[t] = ssc[t] - v;
  }
  __syncthreads();
#pragma unroll
  for (int k = 0; k < EPT; ++k) {
    if (myd[k] >= 0) {
      int b = myd[k] >> 8;
      int pos = atomicAdd(&scnt[b], 1);
      pairs[pos] = (uint)mys[k] | ((uint)(myd[k] & 255) << 16);
      bid[pos] = (unsigned char)b;
    }
  }
  __syncthreads();
  for (int i = t; i < tcount; i += 256) {
    int b = bid[i];
    pbuf[((size_t)b << 13) + gbase[b] + (i - soff[b])] = pairs[i];
  }
}

// ---------------- pass 2: per-bucket fill -> csrc (u16), rp (+sentinel), dinv ----------------

__global__ __launch_bounds__(256) void k_fill2(const uint* __restrict__ pbuf, const int* __restrict__ gcur,
                                               ushort* __restrict__ csrc, int* __restrict__ rp,
                                               float* __restrict__ dinv) {
  __shared__ int sv[256], ssc[256], loff[256], lcur[256], lcnt[256];
  const int b = blockIdx.x;
  const int t = threadIdx.x;
  const int n0 = b * 256;
  const int nn = min(256, NN - n0);

  int gv = (t < NB) ? gcur[t] : 0;
  sv[t] = gv;
  ssc[t] = gv;
  __syncthreads();
  for (int d = 1; d < 256; d <<= 1) {
    int x = (t >= d) ? ssc[t - d] : 0;
    __syncthreads();
    ssc[t] += x;
    __syncthreads();
  }
  const int beg = ssc[b] - sv[b];
  const int len = sv[b];
  const uint* pb = pbuf + ((size_t)b << 13);
  __syncthreads();

  lcnt[t] = 0;
  __syncthreads();
  for (int i = t; i < len; i += 256) {
    atomicAdd(&lcnt[pb[i] >> 16], 1);
  }
  __syncthreads();
  int v = lcnt[t];
  ssc[t] = v;
  __syncthreads();
  for (int d = 1; d < 256; d <<= 1) {
    int x = (t >= d) ? ssc[t - d] : 0;
    __syncthreads();
    ssc[t] += x;
    __syncthreads();
  }
  loff[t] = ssc[t] - v;
  lcur[t] = ssc[t] - v;
  if (t < nn) {
    rp[n0 + t] = beg + loff[t];
    dinv[n0 + t] = rsqrtf((float)(v + 1));  // +1 self loop
  }
  if (b == NB - 1 && t == nn) rp[NN] = beg + loff[t];  // sentinel = NE
  __syncthreads();
  for (int i = t; i < len; i += 256) {
    uint p = pb[i];
    int slot = atomicAdd(&lcur[p >> 16], 1);
    csrc[beg + slot] = (ushort)(p & 0xffff);
  }
}

// ---------------- GEMM (layer 1 only): T' = dinv * (x @ W1), LDS-free fp16 MFMA ----------------

__global__ __launch_bounds__(256) void k_gemm0(const float* __restrict__ Af, const uint4* __restrict__ whf,
                                               const float* __restrict__ dinv, ushort* __restrict__ T) {
  const int t = threadIdx.x;
  const int w = t >> 6;
  const int l = t & 63;
  const int lr = l & 15;
  const int lk = l >> 4;
  const int row = blockIdx.x * 64 + w * 16 + lr;
  const int rc = min(row, NN - 1);

  f16x8 afr[4];
  const float4* ar = (const float4*)(Af + (size_t)rc * CH);
#pragma unroll
  for (int ks = 0; ks < 4; ++ks) {
    float4 a0 = ar[ks * 8 + lk * 2];
    float4 a1 = ar[ks * 8 + lk * 2 + 1];
    uint4 u;
    u.x = (uint)f2h(a0.x) | ((uint)f2h(a0.y) << 16);
    u.y = (uint)f2h(a0.z) | ((uint)f2h(a0.w) << 16);
    u.z = (uint)f2h(a1.x) | ((uint)f2h(a1.y) << 16);
    u.w = (uint)f2h(a1.z) | ((uint)f2h(a1.w) << 16);
    afr[ks] = __builtin_bit_cast(f16x8, u);
  }

  f32x4 acc[8];
#pragma unroll
  for (int nt = 0; nt < 8; ++nt) acc[nt] = (f32x4)(0.f);

#pragma unroll
  for (int ks = 0; ks < 4; ++ks) {
#pragma unroll
    for (int nt = 0; nt < 8; ++nt) {
      f16x8 bh = __builtin_bit_cast(f16x8, whf[(ks * 8 + nt) * 64 + l]);
      acc[nt] = __builtin_amdgcn_mfma_f32_16x16x32_f16(bh, afr[ks], acc[nt], 0, 0, 0);
    }
  }

  if (row < NN) {
    float d = dinv[row];
    ushort* tr = T + (size_t)row * CH + lk * 4;
#pragma unroll
    for (int nt = 0; nt < 8; ++nt) {
      uint2 pk;
      pk.x = (uint)f2h(acc[nt][0] * d) | ((uint)f2h(acc[nt][1] * d) << 16);
      pk.y = (uint)f2h(acc[nt][2] * d) | ((uint)f2h(acc[nt][3] * d) << 16);
      *(uint2*)(tr + nt * 16) = pk;
    }
  }
}

// ---------------- Fused agg + next-layer GEMM ----------------
// block = 64 nodes, 256 threads. Phase 1: 16 quarter-waves x 4 sequential nodes:
// h = relu(b + dinv*(T'self + sum T'src)) -> fp16 into swizzled LDS [64][128].
// Phase 2: 4 waves x 16-row strips, swapped-operand MFMA vs whf (next W),
// write Tout = dinv * (h @ W) packed fp16. Same rounding points as split kernels.

__global__ __launch_bounds__(256) void k_aggemm(const ushort* __restrict__ Tp, const int* __restrict__ rp,
                                                const ushort* __restrict__ csrc,
                                                const float* __restrict__ dinv, const float* __restrict__ b,
                                                const uint4* __restrict__ whf, ushort* __restrict__ Tout) {
  __shared__ ushort sH[64 * 128];  // 16 KB
  const int t = threadIdx.x;
  const int qw = t >> 4;   // quarter-wave 0..15
  const int q = t & 15;    // channels 8q..8q+7
  const int nbase = blockIdx.x * 64;
  const uint4* T16 = (const uint4*)Tp;

  float4 bb0 = ((const float4*)b)[q * 2];
  float4 bb1 = ((const float4*)b)[q * 2 + 1];

#pragma unroll 1
  for (int i = 0; i < 4; ++i) {
    const int row = qw * 4 + i;
    const int node = min(nbase + row, NN - 1);
    float a[8];
    h8_unpack(T16[(size_t)node * 16 + q], a);  // self term
    gather_acc(T16, csrc, rp[node], rp[node + 1] - rp[node], q, a);
    const float d = dinv[node];
    ushort hh[8];
    hh[0] = f2h(fmaxf(fmaf(d, a[0], bb0.x), 0.f));
    hh[1] = f2h(fmaxf(fmaf(d, a[1], bb0.y), 0.f));
    hh[2] = f2h(fmaxf(fmaf(d, a[2], bb0.z), 0.f));
    hh[3] = f2h(fmaxf(fmaf(d, a[3], bb0.w), 0.f));
    hh[4] = f2h(fmaxf(fmaf(d, a[4], bb1.x), 0.f));
    hh[5] = f2h(fmaxf(fmaf(d, a[5], bb1.y), 0.f));
    hh[6] = f2h(fmaxf(fmaf(d, a[6], bb1.z), 0.f));
    hh[7] = f2h(fmaxf(fmaf(d, a[7], bb1.w), 0.f));
    uint4 u;
    u.x = (uint)hh[0] | ((uint)hh[1] << 16);
    u.y = (uint)hh[2] | ((uint)hh[3] << 16);
    u.z = (uint)hh[4] | ((uint)hh[5] << 16);
    u.w = (uint)hh[6] | ((uint)hh[7] << 16);
    int idx = (row * 128 + q * 8) ^ ((row & 7) << 3);
    *(uint4*)&sH[idx] = u;
  }
  __syncthreads();

  // GEMM phase
  const int w = t >> 6;
  const int l = t & 63;
  const int lr = l & 15;
  const int lk = l >> 4;
  const int arow = w * 16 + lr;

  f16x8 afr[4];
#pragma unroll
  for (int ks = 0; ks < 4; ++ks) {
    int idx = (arow * 128 + ks * 32 + lk * 8) ^ ((arow & 7) << 3);
    afr[ks] = __builtin_bit_cast(f16x8, *(const uint4*)&sH[idx]);
  }

  f32x4 acc[8];
#pragma unroll
  for (int nt = 0; nt < 8; ++nt) acc[nt] = (f32x4)(0.f);

#pragma unroll
  for (int ks = 0; ks < 4; ++ks) {
#pragma unroll
    for (int nt = 0; nt < 8; ++nt) {
      f16x8 bh = __builtin_bit_cast(f16x8, whf[(ks * 8 + nt) * 64 + l]);
      acc[nt] = __builtin_amdgcn_mfma_f32_16x16x32_f16(bh, afr[ks], acc[nt], 0, 0, 0);
    }
  }

  const int row = nbase + arow;
  if (row < NN) {
    float d = dinv[row];
    ushort* tr = Tout + (size_t)row * CH + lk * 4;
#pragma unroll
    for (int nt = 0; nt < 8; ++nt) {
      uint2 pk;
      pk.x = (uint)f2h(acc[nt][0] * d) | ((uint)f2h(acc[nt][1] * d) << 16);
      pk.y = (uint)f2h(acc[nt][2] * d) | ((uint)f2h(acc[nt][3] * d) << 16);
      *(uint2*)(tr + nt * 16) = pk;
    }
  }
}

// ---------------- Final aggregation (layer 3) + fused mean-pool partial ----------------

__global__ __launch_bounds__(256) void k_agg3(const ushort* __restrict__ Tp, const int* __restrict__ rp,
                                              const ushort* __restrict__ csrc,
                                              const float* __restrict__ dinv, const float* __restrict__ b,
                                              float* __restrict__ outf,
                                              const int* __restrict__ batch, float* __restrict__ gsum) {
  const int nb = threadIdx.x >> 4;
  const int node = blockIdx.x * 16 + nb;  // grid exact: 3125*16
  const int q = threadIdx.x & 15;
  const uint4* T16 = (const uint4*)Tp;

  float a[8];
  h8_unpack(T16[(size_t)node * 16 + q], a);  // self term
  gather_acc(T16, csrc, rp[node], rp[node + 1] - rp[node], q, a);

  const float d = dinv[node];
  float4 bb0 = ((const float4*)b)[q * 2];
  float4 bb1 = ((const float4*)b)[q * 2 + 1];
  float o[8];
  o[0] = fmaf(d, a[0], bb0.x); o[1] = fmaf(d, a[1], bb0.y);
  o[2] = fmaf(d, a[2], bb0.z); o[3] = fmaf(d, a[3], bb0.w);
  o[4] = fmaf(d, a[4], bb1.x); o[5] = fmaf(d, a[5], bb1.y);
  o[6] = fmaf(d, a[6], bb1.z); o[7] = fmaf(d, a[7], bb1.w);

  float4* of = (float4*)outf;
  of[(size_t)node * 32 + q * 2] = make_float4(o[0], o[1], o[2], o[3]);
  of[(size_t)node * 32 + q * 2 + 1] = make_float4(o[4], o[5], o[6], o[7]);

  // fused mean-pool partial
  __shared__ float oall[16][CH];
  __shared__ int gids[16];
  *(float4*)&oall[nb][q * 8] = make_float4(o[0], o[1], o[2], o[3]);
  *(float4*)&oall[nb][q * 8 + 4] = make_float4(o[4], o[5], o[6], o[7]);
  if (q == 0) gids[nb] = batch[node];
  __syncthreads();
  const int c = threadIdx.x & 127;
  const int half = threadIdx.x >> 7;
  int curg = gids[half * 8];
  float run = 0.f;
#pragma unroll
  for (int n = 0; n < 8; ++n) {
    int r = half * 8 + n;
    int g = gids[r];
    if (g != curg) {
      atomicAdd(&gsum[curg * CH + c], run);
      run = 0.f;
      curg = g;
    }
    run += oall[r][c];
  }
  atomicAdd(&gsum[curg * CH + c], run);
}

// ---------------- Pool finish: divide by count + g @ Wl + bl ----------------

__global__ __launch_bounds__(128) void k_pool2(const float* __restrict__ gsum,
                                               const int* __restrict__ batch,
                                               const float* __restrict__ Wl,
                                               const float* __restrict__ bl,
                                               float* __restrict__ gout) {
  int g = blockIdx.x;
  int c = threadIdx.x;
  int lo = 0, hi = NN;
  while (lo < hi) { int m = (lo + hi) >> 1; if (batch[m] < g) lo = m + 1; else hi = m; }
  int beg = lo;
  hi = NN;
  while (lo < hi) { int m = (lo + hi) >> 1; if (batch[m] < g + 1) lo = m + 1; else hi = m; }
  int end = lo;
  float gv = gsum[g * CH + c] / fmaxf((float)(end - beg), 1.0f);

  __shared__ float sg[CH];
  sg[c] = gv;
  __syncthreads();
  if (c < OC) {
    float o = bl[c];
    for (int k = 0; k < CH; ++k) o = fmaf(sg[k], Wl[k * OC + c], o);
    gout[g * OC + c] = o;
  }
}

// ---------------- launch ----------------

extern "C" void kernel_launch(void* const* d_in, const int* in_sizes, int n_in,
                              void* d_out, int out_size, void* d_ws, size_t ws_size,
                              hipStream_t stream) {
  const float* x = (const float*)d_in[0];
  const int* ei = (const int*)d_in[1];
  const int* src = ei;
  const int* dst = ei + NE;
  const int* batch = (const int*)d_in[2];
  const float* W1 = (const float*)d_in[3];
  const float* b1 = (const float*)d_in[4];
  const float* W2 = (const float*)d_in[5];
  const float* b2 = (const float*)d_in[6];
  const float* W3 = (const float*)d_in[7];
  const float* b3 = (const float*)d_in[8];
  const float* Wl = (const float*)d_in[9];
  const float* bl = (const float*)d_in[10];

  char* ws = (char*)d_ws;
  size_t off = 0;
  auto alloc = [&](size_t bytes) {
    void* p = ws + off;
    off += (bytes + 255) & ~(size_t)255;
    return p;
  };
  float* dinv = (float*)alloc(NN * 4);
  int* rp = (int*)alloc((NN + 1) * 4);
  int* gcur = (int*)alloc(NB * 4);
  ushort* csrc = (ushort*)alloc((size_t)NE * 2);          // 1.6 MB (u16 src ids)
  uint* pbuf = (uint*)alloc((size_t)NB * PCAP * 4);       // 6.4 MB packed
  ushort* tbufA = (ushort*)alloc((size_t)NN * CH * 2);    // T' ping
  ushort* tbufB = (ushort*)alloc((size_t)NN * CH * 2);    // T' pong
  float* gsum = (float*)alloc((size_t)NG * CH * 4);
  uint4* whf = (uint4*)alloc(3 * 2048 * sizeof(uint4));   // 96 KB fp16 W frags

  float* gout = (float*)d_out;
  float* nemb = (float*)d_out + NG * OC;

  const int nb_g = (NN + 63) / 64;          // 782
  const int nb_a = NN / 16;                 // 3125
  const int nb_t = (NE + TILE - 1) / TILE;  // 196 bin tiles

  k_prep<<<4, 256, 0, stream>>>(W1, W2, W3, whf, gcur, gsum);  // + zero duty
  k_bin<<<nb_t, 256, 0, stream>>>(src, dst, gcur, pbuf);
  k_fill2<<<NB, 256, 0, stream>>>(pbuf, gcur, csrc, rp, dinv);

  // layer 1 GEMM: T1' = dinv*(x @ W1)
  k_gemm0<<<nb_g, 256, 0, stream>>>(x, whf + 0 * 2048, dinv, tbufA);
  // fused: h1 = relu(agg(T1')+b1); T2' = dinv*(h1 @ W2)
  k_aggemm<<<nb_g, 256, 0, stream>>>(tbufA, rp, csrc, dinv, b1, whf + 1 * 2048, tbufB);
  // fused: h2 = relu(agg(T2')+b2); T3' = dinv*(h2 @ W3)
  k_aggemm<<<nb_g, 256, 0, stream>>>(tbufB, rp, csrc, dinv, b2, whf + 2 * 2048, tbufA);
  // final agg -> n_emb (fp32, into d_out) + fused pool partial
  k_agg3<<<nb_a, 256, 0, stream>>>(tbufA, rp, csrc, dinv, b3, nemb, batch, gsum);
  // pool finish
  k_pool2<<<NG, 128, 0, stream>>>(gsum, batch, Wl, bl, gout);
}

// Round 13
// 156.359 us; speedup vs baseline: 1.2625x; 1.0924x over previous
//
#include <hip/hip_runtime.h>
#include <hip/hip_fp16.h>

#define NN 50000
#define NE 800000
#define CH 128
#define NG 64
#define OC 10

#define NB 196        // ceil(50000/256) coarse buckets of 256 nodes
#define TILE 4096     // edges per k_bin tile
#define PCAP 8192     // pbuf slots per bucket
#define EPT 16        // edges per thread in k_bin (TILE/256)

typedef _Float16 f16x8 __attribute__((ext_vector_type(8)));
typedef float f32x4 __attribute__((ext_vector_type(4)));

__device__ inline ushort f2h(float x) { __half h = __float2half(x); return __half_as_ushort(h); }
__device__ inline float h2f(ushort u) { return __half2float(__ushort_as_half(u)); }

__device__ inline void h8_unpack(const uint4 u, float* f) {
  f[0] = h2f((ushort)(u.x & 0xffff)); f[1] = h2f((ushort)(u.x >> 16));
  f[2] = h2f((ushort)(u.y & 0xffff)); f[3] = h2f((ushort)(u.y >> 16));
  f[4] = h2f((ushort)(u.z & 0xffff)); f[5] = h2f((ushort)(u.z >> 16));
  f[6] = h2f((ushort)(u.w & 0xffff)); f[7] = h2f((ushort)(u.w >> 16));
}

// shared gather body: accumulate sum of T'[src] rows into a[8] (channels 8q..8q+7)
__device__ inline void gather_acc(const uint4* __restrict__ T16, const ushort* __restrict__ csrc,
                                  int beg, int num, int q, float* a) {
  int e = 0;
  for (; e + 3 < num; e += 4) {
    int s0 = csrc[beg + e];
    int s1 = csrc[beg + e + 1];
    int s2 = csrc[beg + e + 2];
    int s3 = csrc[beg + e + 3];
    uint4 m0 = T16[(size_t)s0 * 16 + q];
    uint4 m1 = T16[(size_t)s1 * 16 + q];
    uint4 m2 = T16[(size_t)s2 * 16 + q];
    uint4 m3 = T16[(size_t)s3 * 16 + q];
    float f0[8], f1[8], f2[8], f3[8];
    h8_unpack(m0, f0); h8_unpack(m1, f1); h8_unpack(m2, f2); h8_unpack(m3, f3);
#pragma unroll
    for (int j = 0; j < 8; ++j) a[j] += (f0[j] + f1[j]) + (f2[j] + f3[j]);
  }
  for (; e < num; ++e) {
    int s = csrc[beg + e];
    float f[8];
    h8_unpack(T16[(size_t)s * 16 + q], f);
#pragma unroll
    for (int j = 0; j < 8; ++j) a[j] += f[j];
  }
}

// ---------------- W fragment prep (+ init duty on block 3) ----------------

__global__ __launch_bounds__(256) void k_prep(const float* __restrict__ W1, const float* __restrict__ W2,
                                              const float* __restrict__ W3, uint4* __restrict__ whf,
                                              int* __restrict__ gcur, float* __restrict__ gsum) {
  if (blockIdx.x == 3) {
    for (int i = threadIdx.x; i < NB; i += 256) gcur[i] = 0;
    for (int i = threadIdx.x; i < NG * CH; i += 256) gsum[i] = 0.f;
    return;
  }
  const float* W = (blockIdx.x == 0) ? W1 : (blockIdx.x == 1) ? W2 : W3;
  uint4* wh = whf + blockIdx.x * 2048;
  for (int idx = threadIdx.x; idx < 2048; idx += 256) {
    int l = idx & 63, f = idx >> 6;
    int ks = f >> 3, nt = f & 7;
    int k0 = ks * 32 + (l >> 4) * 8;
    int col = nt * 16 + (l & 15);
    ushort h[8];
#pragma unroll
    for (int j = 0; j < 8; ++j) h[j] = f2h(W[(k0 + j) * CH + col]);
    uint4 u;
    u.x = (unsigned)h[0] | ((unsigned)h[1] << 16);
    u.y = (unsigned)h[2] | ((unsigned)h[3] << 16);
    u.z = (unsigned)h[4] | ((unsigned)h[5] << 16);
    u.w = (unsigned)h[6] | ((unsigned)h[7] << 16);
    wh[idx] = u;
  }
}

// ---------------- pass 1: bin edges into 196 coarse buckets, LDS-staged ----------------

__global__ __launch_bounds__(256) void k_bin(const int* __restrict__ src, const int* __restrict__ dst,
                                             int* __restrict__ gcur, uint* __restrict__ pbuf) {
  __shared__ int scnt[NB];
  __shared__ int soff[NB];
  __shared__ int gbase[NB];
  __shared__ int ssc[256];
  __shared__ uint pairs[TILE];
  __shared__ unsigned char bid[TILE];
  const int t = threadIdx.x;
  const int tile0 = blockIdx.x * TILE;
  const int tcount = min(TILE, NE - tile0);

  int myd[EPT], mys[EPT];
#pragma unroll
  for (int k = 0; k < EPT; ++k) {
    int i = t + k * 256;
    if (i < tcount) {
      myd[k] = dst[tile0 + i];
      mys[k] = src[tile0 + i];
    } else {
      myd[k] = -1;
    }
  }

  for (int i = t; i < NB; i += 256) scnt[i] = 0;
  __syncthreads();
#pragma unroll
  for (int k = 0; k < EPT; ++k) {
    if (myd[k] >= 0) atomicAdd(&scnt[myd[k] >> 8], 1);
  }
  __syncthreads();
  int v = (t < NB) ? scnt[t] : 0;
  ssc[t] = v;
  __syncthreads();
  for (int d2 = 1; d2 < 256; d2 <<= 1) {
    int x2 = (t >= d2) ? ssc[t - d2] : 0;
    __syncthreads();
    ssc[t] += x2;
    __syncthreads();
  }
  if (t < NB) {
    soff[t] = ssc[t] - v;
    gbase[t] = (v > 0) ? atomicAdd(&gcur[t], v) : 0;
    scnt[t] = ssc[t] - v;
  }
  __syncthreads();
#pragma unroll
  for (int k = 0; k < EPT; ++k) {
    if (myd[k] >= 0) {
      int b = myd[k] >> 8;
      int pos = atomicAdd(&scnt[b], 1);
      pairs[pos] = (uint)mys[k] | ((uint)(myd[k] & 255) << 16);
      bid[pos] = (unsigned char)b;
    }
  }
  __syncthreads();
  for (int i = t; i < tcount; i += 256) {
    int b = bid[i];
    pbuf[((size_t)b << 13) + gbase[b] + (i - soff[b])] = pairs[i];
  }
}

// ---------------- pass 2: per-bucket fill -> csrc (u16), rp (+sentinel), dinv ----------------

__global__ __launch_bounds__(256) void k_fill2(const uint* __restrict__ pbuf, const int* __restrict__ gcur,
                                               ushort* __restrict__ csrc, int* __restrict__ rp,
                                               float* __restrict__ dinv) {
  __shared__ int sv[256], ssc[256], loff[256], lcur[256], lcnt[256];
  const int b = blockIdx.x;
  const int t = threadIdx.x;
  const int n0 = b * 256;
  const int nn = min(256, NN - n0);

  int gv = (t < NB) ? gcur[t] : 0;
  sv[t] = gv;
  ssc[t] = gv;
  __syncthreads();
  for (int d = 1; d < 256; d <<= 1) {
    int x = (t >= d) ? ssc[t - d] : 0;
    __syncthreads();
    ssc[t] += x;
    __syncthreads();
  }
  const int beg = ssc[b] - sv[b];
  const int len = sv[b];
  const uint* pb = pbuf + ((size_t)b << 13);
  __syncthreads();

  lcnt[t] = 0;
  __syncthreads();
  for (int i = t; i < len; i += 256) {
    atomicAdd(&lcnt[pb[i] >> 16], 1);
  }
  __syncthreads();
  int v = lcnt[t];
  ssc[t] = v;
  __syncthreads();
  for (int d = 1; d < 256; d <<= 1) {
    int x = (t >= d) ? ssc[t - d] : 0;
    __syncthreads();
    ssc[t] += x;
    __syncthreads();
  }
  loff[t] = ssc[t] - v;
  lcur[t] = ssc[t] - v;
  if (t < nn) {
    rp[n0 + t] = beg + loff[t];
    dinv[n0 + t] = rsqrtf((float)(v + 1));  // +1 self loop
  }
  if (b == NB - 1 && t == nn) rp[NN] = beg + loff[t];  // sentinel = NE
  __syncthreads();
  for (int i = t; i < len; i += 256) {
    uint p = pb[i];
    int slot = atomicAdd(&lcur[p >> 16], 1);
    csrc[beg + slot] = (ushort)(p & 0xffff);
  }
}

// ---------------- GEMM (layer 1 only): T' = dinv * (x @ W1), LDS-free fp16 MFMA ----------------

__global__ __launch_bounds__(256) void k_gemm0(const float* __restrict__ Af, const uint4* __restrict__ whf,
                                               const float* __restrict__ dinv, ushort* __restrict__ T) {
  const int t = threadIdx.x;
  const int w = t >> 6;
  const int l = t & 63;
  const int lr = l & 15;
  const int lk = l >> 4;
  const int row = blockIdx.x * 64 + w * 16 + lr;
  const int rc = min(row, NN - 1);

  f16x8 afr[4];
  const float4* ar = (const float4*)(Af + (size_t)rc * CH);
#pragma unroll
  for (int ks = 0; ks < 4; ++ks) {
    float4 a0 = ar[ks * 8 + lk * 2];
    float4 a1 = ar[ks * 8 + lk * 2 + 1];
    uint4 u;
    u.x = (uint)f2h(a0.x) | ((uint)f2h(a0.y) << 16);
    u.y = (uint)f2h(a0.z) | ((uint)f2h(a0.w) << 16);
    u.z = (uint)f2h(a1.x) | ((uint)f2h(a1.y) << 16);
    u.w = (uint)f2h(a1.z) | ((uint)f2h(a1.w) << 16);
    afr[ks] = __builtin_bit_cast(f16x8, u);
  }

  f32x4 acc[8];
#pragma unroll
  for (int nt = 0; nt < 8; ++nt) acc[nt] = (f32x4)(0.f);

#pragma unroll
  for (int ks = 0; ks < 4; ++ks) {
#pragma unroll
    for (int nt = 0; nt < 8; ++nt) {
      f16x8 bh = __builtin_bit_cast(f16x8, whf[(ks * 8 + nt) * 64 + l]);
      acc[nt] = __builtin_amdgcn_mfma_f32_16x16x32_f16(bh, afr[ks], acc[nt], 0, 0, 0);
    }
  }

  if (row < NN) {
    float d = dinv[row];
    ushort* tr = T + (size_t)row * CH + lk * 4;
#pragma unroll
    for (int nt = 0; nt < 8; ++nt) {
      uint2 pk;
      pk.x = (uint)f2h(acc[nt][0] * d) | ((uint)f2h(acc[nt][1] * d) << 16);
      pk.y = (uint)f2h(acc[nt][2] * d) | ((uint)f2h(acc[nt][3] * d) << 16);
      *(uint2*)(tr + nt * 16) = pk;
    }
  }
}

// ---------------- Fused agg + next-layer GEMM (16 nodes/block, grid 3125) ----------------
// Phase 1: one node per quarter-wave (50K concurrent gather chains, as in split k_agg):
// h = relu(b + dinv*(T'self + sum T'src)) -> fp16 into swizzled LDS [16][128].
// Phase 2: 4 waves; each computes the full 16-row strip x 2 of the 8 col-tiles.
// Same rounding points as the split kernels.

__global__ __launch_bounds__(256) void k_aggemm(const ushort* __restrict__ Tp, const int* __restrict__ rp,
                                                const ushort* __restrict__ csrc,
                                                const float* __restrict__ dinv, const float* __restrict__ b,
                                                const uint4* __restrict__ whf, ushort* __restrict__ Tout) {
  __shared__ ushort sH[16 * 128];  // 4 KB
  const int t = threadIdx.x;
  const int qw = t >> 4;   // quarter-wave = node-in-block 0..15
  const int q = t & 15;    // channels 8q..8q+7
  const int nbase = blockIdx.x * 16;  // grid exact: 3125*16
  const uint4* T16 = (const uint4*)Tp;

  {
    const int node = nbase + qw;
    float4 bb0 = ((const float4*)b)[q * 2];
    float4 bb1 = ((const float4*)b)[q * 2 + 1];
    float a[8];
    h8_unpack(T16[(size_t)node * 16 + q], a);  // self term
    gather_acc(T16, csrc, rp[node], rp[node + 1] - rp[node], q, a);
    const float d = dinv[node];
    ushort hh[8];
    hh[0] = f2h(fmaxf(fmaf(d, a[0], bb0.x), 0.f));
    hh[1] = f2h(fmaxf(fmaf(d, a[1], bb0.y), 0.f));
    hh[2] = f2h(fmaxf(fmaf(d, a[2], bb0.z), 0.f));
    hh[3] = f2h(fmaxf(fmaf(d, a[3], bb0.w), 0.f));
    hh[4] = f2h(fmaxf(fmaf(d, a[4], bb1.x), 0.f));
    hh[5] = f2h(fmaxf(fmaf(d, a[5], bb1.y), 0.f));
    hh[6] = f2h(fmaxf(fmaf(d, a[6], bb1.z), 0.f));
    hh[7] = f2h(fmaxf(fmaf(d, a[7], bb1.w), 0.f));
    uint4 u;
    u.x = (uint)hh[0] | ((uint)hh[1] << 16);
    u.y = (uint)hh[2] | ((uint)hh[3] << 16);
    u.z = (uint)hh[4] | ((uint)hh[5] << 16);
    u.w = (uint)hh[6] | ((uint)hh[7] << 16);
    int idx = (qw * 128 + q * 8) ^ ((qw & 7) << 3);
    *(uint4*)&sH[idx] = u;
  }
  __syncthreads();

  // GEMM phase: wave w -> col tiles nt = 2w, 2w+1 over the 16-row strip
  const int w = t >> 6;
  const int l = t & 63;
  const int lr = l & 15;
  const int lk = l >> 4;

  f16x8 afr[4];
#pragma unroll
  for (int ks = 0; ks < 4; ++ks) {
    int idx = (lr * 128 + ks * 32 + lk * 8) ^ ((lr & 7) << 3);
    afr[ks] = __builtin_bit_cast(f16x8, *(const uint4*)&sH[idx]);
  }

  f32x4 acc[2];
  acc[0] = (f32x4)(0.f);
  acc[1] = (f32x4)(0.f);

#pragma unroll
  for (int ks = 0; ks < 4; ++ks) {
    f16x8 b0 = __builtin_bit_cast(f16x8, whf[(ks * 8 + w * 2) * 64 + l]);
    f16x8 b1 = __builtin_bit_cast(f16x8, whf[(ks * 8 + w * 2 + 1) * 64 + l]);
    acc[0] = __builtin_amdgcn_mfma_f32_16x16x32_f16(b0, afr[ks], acc[0], 0, 0, 0);
    acc[1] = __builtin_amdgcn_mfma_f32_16x16x32_f16(b1, afr[ks], acc[1], 0, 0, 0);
  }

  {
    const int row = nbase + lr;  // always < NN (grid exact)
    float d = dinv[row];
    ushort* tr = Tout + (size_t)row * CH + lk * 4;
#pragma unroll
    for (int j = 0; j < 2; ++j) {
      uint2 pk;
      pk.x = (uint)f2h(acc[j][0] * d) | ((uint)f2h(acc[j][1] * d) << 16);
      pk.y = (uint)f2h(acc[j][2] * d) | ((uint)f2h(acc[j][3] * d) << 16);
      *(uint2*)(tr + (w * 2 + j) * 16) = pk;
    }
  }
}

// ---------------- Final aggregation (layer 3) + fused mean-pool partial ----------------

__global__ __launch_bounds__(256) void k_agg3(const ushort* __restrict__ Tp, const int* __restrict__ rp,
                                              const ushort* __restrict__ csrc,
                                              const float* __restrict__ dinv, const float* __restrict__ b,
                                              float* __restrict__ outf,
                                              const int* __restrict__ batch, float* __restrict__ gsum) {
  const int nb = threadIdx.x >> 4;
  const int node = blockIdx.x * 16 + nb;  // grid exact: 3125*16
  const int q = threadIdx.x & 15;
  const uint4* T16 = (const uint4*)Tp;

  float a[8];
  h8_unpack(T16[(size_t)node * 16 + q], a);  // self term
  gather_acc(T16, csrc, rp[node], rp[node + 1] - rp[node], q, a);

  const float d = dinv[node];
  float4 bb0 = ((const float4*)b)[q * 2];
  float4 bb1 = ((const float4*)b)[q * 2 + 1];
  float o[8];
  o[0] = fmaf(d, a[0], bb0.x); o[1] = fmaf(d, a[1], bb0.y);
  o[2] = fmaf(d, a[2], bb0.z); o[3] = fmaf(d, a[3], bb0.w);
  o[4] = fmaf(d, a[4], bb1.x); o[5] = fmaf(d, a[5], bb1.y);
  o[6] = fmaf(d, a[6], bb1.z); o[7] = fmaf(d, a[7], bb1.w);

  float4* of = (float4*)outf;
  of[(size_t)node * 32 + q * 2] = make_float4(o[0], o[1], o[2], o[3]);
  of[(size_t)node * 32 + q * 2 + 1] = make_float4(o[4], o[5], o[6], o[7]);

  // fused mean-pool partial
  __shared__ float oall[16][CH];
  __shared__ int gids[16];
  *(float4*)&oall[nb][q * 8] = make_float4(o[0], o[1], o[2], o[3]);
  *(float4*)&oall[nb][q * 8 + 4] = make_float4(o[4], o[5], o[6], o[7]);
  if (q == 0) gids[nb] = batch[node];
  __syncthreads();
  const int c = threadIdx.x & 127;
  const int half = threadIdx.x >> 7;
  int curg = gids[half * 8];
  float run = 0.f;
#pragma unroll
  for (int n = 0; n < 8; ++n) {
    int r = half * 8 + n;
    int g = gids[r];
    if (g != curg) {
      atomicAdd(&gsum[curg * CH + c], run);
      run = 0.f;
      curg = g;
    }
    run += oall[r][c];
  }
  atomicAdd(&gsum[curg * CH + c], run);
}

// ---------------- Pool finish: divide by count + g @ Wl + bl ----------------

__global__ __launch_bounds__(128) void k_pool2(const float* __restrict__ gsum,
                                               const int* __restrict__ batch,
                                               const float* __restrict__ Wl,
                                               const float* __restrict__ bl,
                                               float* __restrict__ gout) {
  int g = blockIdx.x;
  int c = threadIdx.x;
  int lo = 0, hi = NN;
  while (lo < hi) { int m = (lo + hi) >> 1; if (batch[m] < g) lo = m + 1; else hi = m; }
  int beg = lo;
  hi = NN;
  while (lo < hi) { int m = (lo + hi) >> 1; if (batch[m] < g + 1) lo = m + 1; else hi = m; }
  int end = lo;
  float gv = gsum[g * CH + c] / fmaxf((float)(end - beg), 1.0f);

  __shared__ float sg[CH];
  sg[c] = gv;
  __syncthreads();
  if (c < OC) {
    float o = bl[c];
    for (int k = 0; k < CH; ++k) o = fmaf(sg[k], Wl[k * OC + c], o);
    gout[g * OC + c] = o;
  }
}

// ---------------- launch ----------------

extern "C" void kernel_launch(void* const* d_in, const int* in_sizes, int n_in,
                              void* d_out, int out_size, void* d_ws, size_t ws_size,
                              hipStream_t stream) {
  const float* x = (const float*)d_in[0];
  const int* ei = (const int*)d_in[1];
  const int* src = ei;
  const int* dst = ei + NE;
  const int* batch = (const int*)d_in[2];
  const float* W1 = (const float*)d_in[3];
  const float* b1 = (const float*)d_in[4];
  const float* W2 = (const float*)d_in[5];
  const float* b2 = (const float*)d_in[6];
  const float* W3 = (const float*)d_in[7];
  const float* b3 = (const float*)d_in[8];
  const float* Wl = (const float*)d_in[9];
  const float* bl = (const float*)d_in[10];

  char* ws = (char*)d_ws;
  size_t off = 0;
  auto alloc = [&](size_t bytes) {
    void* p = ws + off;
    off += (bytes + 255) & ~(size_t)255;
    return p;
  };
  float* dinv = (float*)alloc(NN * 4);
  int* rp = (int*)alloc((NN + 1) * 4);
  int* gcur = (int*)alloc(NB * 4);
  ushort* csrc = (ushort*)alloc((size_t)NE * 2);          // 1.6 MB (u16 src ids)
  uint* pbuf = (uint*)alloc((size_t)NB * PCAP * 4);       // 6.4 MB packed
  ushort* tbufA = (ushort*)alloc((size_t)NN * CH * 2);    // T' ping
  ushort* tbufB = (ushort*)alloc((size_t)NN * CH * 2);    // T' pong
  float* gsum = (float*)alloc((size_t)NG * CH * 4);
  uint4* whf = (uint4*)alloc(3 * 2048 * sizeof(uint4));   // 96 KB fp16 W frags

  float* gout = (float*)d_out;
  float* nemb = (float*)d_out + NG * OC;

  const int nb_g = (NN + 63) / 64;          // 782
  const int nb_a = NN / 16;                 // 3125
  const int nb_t = (NE + TILE - 1) / TILE;  // 196 bin tiles

  k_prep<<<4, 256, 0, stream>>>(W1, W2, W3, whf, gcur, gsum);  // + zero duty
  k_bin<<<nb_t, 256, 0, stream>>>(src, dst, gcur, pbuf);
  k_fill2<<<NB, 256, 0, stream>>>(pbuf, gcur, csrc, rp, dinv);

  // layer 1 GEMM: T1' = dinv*(x @ W1)
  k_gemm0<<<nb_g, 256, 0, stream>>>(x, whf + 0 * 2048, dinv, tbufA);
  // fused: h1 = relu(agg(T1')+b1); T2' = dinv*(h1 @ W2)
  k_aggemm<<<nb_a, 256, 0, stream>>>(tbufA, rp, csrc, dinv, b1, whf + 1 * 2048, tbufB);
  // fused: h2 = relu(agg(T2')+b2); T3' = dinv*(h2 @ W3)
  k_aggemm<<<nb_a, 256, 0, stream>>>(tbufB, rp, csrc, dinv, b2, whf + 2 * 2048, tbufA);
  // final agg -> n_emb (fp32, into d_out) + fused pool partial
  k_agg3<<<nb_a, 256, 0, stream>>>(tbufA, rp, csrc, dinv, b3, nemb, batch, gsum);
  // pool finish
  k_pool2<<<NG, 128, 0, stream>>>(gsum, batch, Wl, bl, gout);
}